// Round 1
// baseline (717.794 us; speedup 1.0000x reference)
//
#include <hip/hip_runtime.h>

#define BB 16
#define LL 2048
#define DD 128
#define SCALE 0.03125f   // 1/sqrt(1024)

#define QT 64
#define KT 64
#define NT (LL/KT)       // 32
#define THREADS 256

using bf16x8 = __attribute__((ext_vector_type(8))) short;
using f32x4  = __attribute__((ext_vector_type(4))) float;
using u16x4  = __attribute__((ext_vector_type(4))) unsigned short;

__device__ __forceinline__ unsigned short f2bf(float f){
    union { float f; unsigned u; } a; a.f = f;
    unsigned r = a.u + 0x7FFFu + ((a.u >> 16) & 1u);
    return (unsigned short)(r >> 16);
}

// Detect mask element layout: 0 = 4-byte int (LSB byte carries value),
// 1 = 1-byte bool, 2 = 4-byte float (top byte carries value for 1.0f).
__global__ void detect_mask(const unsigned* __restrict__ m, int* __restrict__ flag){
    int lane = threadIdx.x & 63;
    unsigned hi = 0, nl = 0;
    #pragma unroll
    for (int i = 0; i < 16; ++i){
        unsigned d = m[lane*16 + i];
        hi |= (d & 0xFFFFFF00u);   // any set bit above byte0
        nl |= (d & 0xFEFEFEFEu);   // any bit that isn't a byte-LSB
    }
    unsigned long long bh = __ballot(hi != 0u);
    unsigned long long bn = __ballot(nl != 0u);
    if (lane == 0){
        int f = 0;
        if (bn != 0ull) f = 2;          // float-like payload
        else if (bh != 0ull) f = 1;     // packed bytes
        flag[0] = f;                    // else int32 0/1
    }
}

__global__ __launch_bounds__(THREADS, 2) void attn_fused(
    const float* __restrict__ q, const float* __restrict__ k, const float* __restrict__ v,
    const unsigned char* __restrict__ maskb, const int* __restrict__ flagp,
    float* __restrict__ out, float* __restrict__ attn)
{
    __shared__ __attribute__((aligned(16))) unsigned short k_s[KT*DD];    // [krow][d^swz]
    __shared__ __attribute__((aligned(16))) unsigned short vT_s[DD*KT];   // [d][kk^swz]
    __shared__ __attribute__((aligned(16))) unsigned short p_s[4*16*KT];  // per-wave [qrow][k^swz]

    const int tid  = threadIdx.x;
    const int w    = tid >> 6;
    const int lane = tid & 63;
    const int ln15 = lane & 15;
    const int g    = lane >> 4;          // 0..3

    const int bidx = blockIdx.x;
    const int bb   = bidx >> 5;          // batch
    const int qt0  = (bidx & 31) * QT;
    const int qw0  = qt0 + w*16;         // this wave's first q row

    // mask addressing: byte offset = (elem_idx << msh) + madd  (uniform)
    const int mflag = flagp[0];
    const int msh   = (mflag == 1) ? 0 : 2;
    const int madd  = (mflag == 2) ? 3 : 0;

    // ---- Q fragments (A-operand): row = ln15, kdim chunk = g*8+j ----
    bf16x8 qa[4];
    {
        const float* qp = q + ((size_t)bb*LL + qw0 + ln15)*DD + g*8;
        #pragma unroll
        for (int c = 0; c < 4; ++c){
            float4 x = *(const float4*)(qp + c*32);
            float4 y = *(const float4*)(qp + c*32 + 4);
            bf16x8 t;
            t[0]=(short)f2bf(x.x); t[1]=(short)f2bf(x.y); t[2]=(short)f2bf(x.z); t[3]=(short)f2bf(x.w);
            t[4]=(short)f2bf(y.x); t[5]=(short)f2bf(y.y); t[6]=(short)f2bf(y.z); t[7]=(short)f2bf(y.w);
            qa[c] = t;
        }
    }

    // per-lane row bases (element index into [B][Lq][Lk]) for its 4 C/D rows
    size_t mrow[4];
    #pragma unroll
    for (int r = 0; r < 4; ++r)
        mrow[r] = ((size_t)bb*LL + (qw0 + 4*g + r)) * (size_t)LL;

    const float* kbase = k + (size_t)bb*LL*DD;
    const float* vbase = v + (size_t)bb*LL*DD;

    float rs[4] = {0.f, 0.f, 0.f, 0.f};

    // ================= pass 1: row sums of exp =================
    for (int t = 0; t < NT; ++t){
        const int kt0 = t * KT;
        __syncthreads();
        {   // stage K tile (bf16, XOR-swizzled rows)
            const float* kp = kbase + (size_t)kt0*DD;
            #pragma unroll
            for (int i = 0; i < 8; ++i){
                int li = i*THREADS + tid;
                int row = li >> 5, c4 = li & 31;
                float4 f = *(const float4*)(kp + row*DD + c4*4);
                int e = (c4*4) ^ (8*(row & 7));
                u16x4 pk = { f2bf(f.x), f2bf(f.y), f2bf(f.z), f2bf(f.w) };
                *(u16x4*)(&k_s[row*DD + e]) = pk;
            }
        }
        __syncthreads();
        #pragma unroll
        for (int cg = 0; cg < 4; ++cg){
            f32x4 acc = {0.f, 0.f, 0.f, 0.f};
            const int krow = cg*16 + ln15;
            const unsigned short* kb = &k_s[krow*DD];
            const int sw = 8*(krow & 7);
            #pragma unroll
            for (int c = 0; c < 4; ++c){
                bf16x8 bf = *(const bf16x8*)(kb + ((c*32 + g*8) ^ sw));
                acc = __builtin_amdgcn_mfma_f32_16x16x32_bf16(qa[c], bf, acc, 0, 0, 0);
            }
            const int kcol = kt0 + cg*16 + ln15;
            #pragma unroll
            for (int r = 0; r < 4; ++r){
                bool msk = maskb[((mrow[r] + kcol) << msh) + madd] != 0;
                rs[r] += msk ? 0.f : __expf(acc[r] * SCALE);
            }
        }
    }

    // reduce row sums across the 16 lanes of each quad-group
    float invl[4];
    #pragma unroll
    for (int r = 0; r < 4; ++r){
        float s = rs[r];
        s += __shfl_xor(s, 1); s += __shfl_xor(s, 2);
        s += __shfl_xor(s, 4); s += __shfl_xor(s, 8);
        invl[r] = 1.0f / s;
    }

    f32x4 oacc[8];
    #pragma unroll
    for (int d8 = 0; d8 < 8; ++d8) oacc[d8] = (f32x4){0.f, 0.f, 0.f, 0.f};

    unsigned short* pw = &p_s[w*16*KT];

    // ================= pass 2: attn write + PV =================
    for (int t = 0; t < NT; ++t){
        const int kt0 = t * KT;
        __syncthreads();
        {   // stage K tile + transposed V tile
            const float* kp = kbase + (size_t)kt0*DD;
            const float* vp = vbase + (size_t)kt0*DD;
            #pragma unroll
            for (int i = 0; i < 8; ++i){
                int li = i*THREADS + tid;
                int row = li >> 5, c4 = li & 31;
                float4 f = *(const float4*)(kp + row*DD + c4*4);
                int e = (c4*4) ^ (8*(row & 7));
                u16x4 pk = { f2bf(f.x), f2bf(f.y), f2bf(f.z), f2bf(f.w) };
                *(u16x4*)(&k_s[row*DD + e]) = pk;
                float4 fv = *(const float4*)(vp + row*DD + c4*4);
                float vv[4] = {fv.x, fv.y, fv.z, fv.w};
                #pragma unroll
                for (int jj = 0; jj < 4; ++jj){
                    int d = c4*4 + jj;
                    vT_s[d*KT + (row ^ (8*(d & 7)))] = f2bf(vv[jj]);
                }
            }
        }
        __syncthreads();
        #pragma unroll
        for (int cg = 0; cg < 4; ++cg){
            f32x4 acc = {0.f, 0.f, 0.f, 0.f};
            const int krow = cg*16 + ln15;
            const unsigned short* kb = &k_s[krow*DD];
            const int sw = 8*(krow & 7);
            #pragma unroll
            for (int c = 0; c < 4; ++c){
                bf16x8 bf = *(const bf16x8*)(kb + ((c*32 + g*8) ^ sw));
                acc = __builtin_amdgcn_mfma_f32_16x16x32_bf16(qa[c], bf, acc, 0, 0, 0);
            }
            const int kcol = kt0 + cg*16 + ln15;
            #pragma unroll
            for (int r = 0; r < 4; ++r){
                bool msk = maskb[((mrow[r] + kcol) << msh) + madd] != 0;
                float p = msk ? 0.f : __expf(acc[r] * SCALE) * invl[r];
                attn[mrow[r] + kcol] = p;              // attn has same indexing as mask
                int prow = 4*g + r;
                pw[prow*KT + ((cg*16 + ln15) ^ (8*(prow & 7)))] = f2bf(p);
            }
        }
        // PV: A = P (from per-wave LDS bounce), B = vT
        bf16x8 pa0 = *(const bf16x8*)(&pw[ln15*KT + (( 0 + g*8) ^ (8*(ln15 & 7)))]);
        bf16x8 pa1 = *(const bf16x8*)(&pw[ln15*KT + ((32 + g*8) ^ (8*(ln15 & 7)))]);
        #pragma unroll
        for (int d8 = 0; d8 < 8; ++d8){
            const int drow = d8*16 + ln15;
            const unsigned short* vb = &vT_s[drow*KT];
            const int swv = 8*(drow & 7);
            bf16x8 b0 = *(const bf16x8*)(vb + (( 0 + g*8) ^ swv));
            bf16x8 b1 = *(const bf16x8*)(vb + ((32 + g*8) ^ swv));
            oacc[d8] = __builtin_amdgcn_mfma_f32_16x16x32_bf16(pa0, b0, oacc[d8], 0, 0, 0);
            oacc[d8] = __builtin_amdgcn_mfma_f32_16x16x32_bf16(pa1, b1, oacc[d8], 0, 0, 0);
        }
    }

    // epilogue: write O
    #pragma unroll
    for (int d8 = 0; d8 < 8; ++d8){
        #pragma unroll
        for (int r = 0; r < 4; ++r){
            out[((size_t)bb*LL + qw0 + 4*g + r)*DD + d8*16 + ln15] = oacc[d8][r];
        }
    }
}

extern "C" void kernel_launch(void* const* d_in, const int* in_sizes, int n_in,
                              void* d_out, int out_size, void* d_ws, size_t ws_size,
                              hipStream_t stream)
{
    const float* q = (const float*)d_in[0];
    const float* k = (const float*)d_in[1];
    const float* v = (const float*)d_in[2];
    const unsigned char* mask = (const unsigned char*)d_in[3];
    int* flag = (int*)d_ws;

    float* out  = (float*)d_out;
    float* attn = out + (size_t)BB*LL*DD;

    detect_mask<<<1, 64, 0, stream>>>((const unsigned*)mask, flag);
    attn_fused<<<BB*(LL/QT), THREADS, 0, stream>>>(q, k, v, mask, flag, out, attn);
}

// Round 2
// 517.252 us; speedup vs baseline: 1.3877x; 1.3877x over previous
//
#include <hip/hip_runtime.h>

#define BB 16
#define LL 2048
#define DD 128
#define SCALE 0.03125f   // 1/sqrt(1024)

#define QT 64
#define KT 64
#define NT (LL/KT)       // 32
#define THREADS 256
#define NWG (BB*(LL/QT))

using bf16x8 = __attribute__((ext_vector_type(8))) short;
using f32x4  = __attribute__((ext_vector_type(4))) float;
using u16x4  = __attribute__((ext_vector_type(4))) unsigned short;
typedef unsigned long long u64;

__device__ __forceinline__ unsigned short f2bf(float f){
    union { float f; unsigned u; } a; a.f = f;
    unsigned r = a.u + 0x7FFFu + ((a.u >> 16) & 1u);
    return (unsigned short)(r >> 16);
}

// Detect mask element layout: 0 = 4-byte int (LSB byte carries value),
// 1 = 1-byte bool, 2 = 4-byte float (payload beyond byte-LSBs).
__global__ void detect_mask(const unsigned* __restrict__ m, int* __restrict__ flag){
    int lane = threadIdx.x & 63;
    unsigned hi = 0, nl = 0;
    #pragma unroll
    for (int i = 0; i < 16; ++i){
        unsigned d = m[lane*16 + i];
        hi |= (d & 0xFFFFFF00u);
        nl |= (d & 0xFEFEFEFEu);
    }
    unsigned long long bh = __ballot(hi != 0u);
    unsigned long long bn = __ballot(nl != 0u);
    if (lane == 0){
        int f = 0;
        if (bn != 0ull) f = 2;
        else if (bh != 0ull) f = 1;
        flag[0] = f;
    }
}

// Pack mask into u64 bitmask: mb[(bb*LL+qrow)*NT + t] bit j = mask[...][t*64+j]
__global__ void prepack_mask(const unsigned char* __restrict__ m,
                             const int* __restrict__ flagp,
                             u64* __restrict__ mb){
    int id = blockIdx.x * THREADS + threadIdx.x;   // one u64 per thread
    int fl = flagp[0];
    u64 bits = 0;
    if (fl == 1){
        const uint4* mp = (const uint4*)(m + (size_t)id * 64);
        #pragma unroll
        for (int c = 0; c < 4; ++c){
            uint4 u = mp[c];
            unsigned wd[4] = {u.x, u.y, u.z, u.w};
            #pragma unroll
            for (int wi = 0; wi < 4; ++wi){
                #pragma unroll
                for (int b = 0; b < 4; ++b)
                    if ((wd[wi] >> (8*b)) & 0xFFu) bits |= 1ull << (c*16 + wi*4 + b);
            }
        }
    } else {
        const uint4* mp = (const uint4*)m + (size_t)id * 16;
        #pragma unroll
        for (int c = 0; c < 16; ++c){
            uint4 u = mp[c];
            if (u.x) bits |= 1ull << (c*4+0);
            if (u.y) bits |= 1ull << (c*4+1);
            if (u.z) bits |= 1ull << (c*4+2);
            if (u.w) bits |= 1ull << (c*4+3);
        }
    }
    mb[id] = bits;
}

template<int USE_BITS>
__global__ __launch_bounds__(THREADS, 3) void attn_fused(
    const float* __restrict__ q, const float* __restrict__ k, const float* __restrict__ v,
    const unsigned char* __restrict__ maskb, const int* __restrict__ flagp,
    const u64* __restrict__ mb,
    float* __restrict__ out, float* __restrict__ attn)
{
    __shared__ __attribute__((aligned(16))) unsigned short k_s[KT*DD];   // 16 KB [krow][d^8*(krow&7)]
    __shared__ __attribute__((aligned(16))) unsigned short vT_s[DD*KT];  // 16 KB [d][k^8*((d>>2)&7)]
    __shared__ __attribute__((aligned(16))) float p_f[4*16*64];          // 16 KB per-wave P f32

    const int tid  = threadIdx.x;
    const int w    = tid >> 6;
    const int lane = tid & 63;
    const int ln15 = lane & 15;
    const int g    = lane >> 4;      // 0..3
    const int r0   = tid >> 5;       // 0..7
    const int c4   = tid & 31;       // 0..31

    const int bidx = blockIdx.x;
    const int bb   = bidx >> 5;
    const int qt0  = (bidx & 31) * QT;
    const int qw0  = qt0 + w*16;

    int msh = 0, madd = 0;
    if (!USE_BITS){
        const int mflag = flagp[0];
        msh  = (mflag == 1) ? 0 : 2;
        madd = (mflag == 2) ? 3 : 0;
    }

    // ---- Q fragments ----
    bf16x8 qa[4];
    {
        const float* qp = q + ((size_t)bb*LL + qw0 + ln15)*DD + g*8;
        #pragma unroll
        for (int c = 0; c < 4; ++c){
            f32x4 x = *(const f32x4*)(qp + c*32);
            f32x4 y = *(const f32x4*)(qp + c*32 + 4);
            bf16x8 t;
            t[0]=(short)f2bf(x[0]); t[1]=(short)f2bf(x[1]); t[2]=(short)f2bf(x[2]); t[3]=(short)f2bf(x[3]);
            t[4]=(short)f2bf(y[0]); t[5]=(short)f2bf(y[1]); t[6]=(short)f2bf(y[2]); t[7]=(short)f2bf(y[3]);
            qa[c] = t;
        }
    }

    size_t mrow[4];
    const u64* mbr[4];
    #pragma unroll
    for (int r = 0; r < 4; ++r){
        size_t qrow = (size_t)bb*LL + qw0 + 4*g + r;
        mrow[r] = qrow * (size_t)LL;
        mbr[r]  = mb + qrow * NT;
    }

    const float* kbase = k + (size_t)bb*LL*DD;
    const float* vbase = v + (size_t)bb*LL*DD;

    f32x4 kpre[8];
    f32x4 vpre[2][4];
    u64 mc[4] = {0,0,0,0}, mn[4] = {0,0,0,0};

#define K_LOAD(T) { const float* kp_ = kbase + (size_t)(T)*KT*DD; \
    _Pragma("unroll") for (int i_ = 0; i_ < 8; ++i_) \
        kpre[i_] = *(const f32x4*)(kp_ + (i_*8 + r0)*DD + c4*4); }

#define K_WRITE() { _Pragma("unroll") for (int i_ = 0; i_ < 8; ++i_){ \
        int row_ = i_*8 + r0; int e_ = (c4*4) ^ (8*(row_ & 7)); \
        u16x4 pk_ = { f2bf(kpre[i_][0]), f2bf(kpre[i_][1]), f2bf(kpre[i_][2]), f2bf(kpre[i_][3]) }; \
        *(u16x4*)(&k_s[row_*DD + e_]) = pk_; } }

#define V_LOAD(T) { const float* vp_ = vbase + (size_t)(T)*KT*DD; \
    _Pragma("unroll") for (int i_ = 0; i_ < 2; ++i_) \
        _Pragma("unroll") for (int rr_ = 0; rr_ < 4; ++rr_) \
            vpre[i_][rr_] = *(const f32x4*)(vp_ + ((r0 + 8*i_)*4 + rr_)*DD + c4*4); }

#define V_WRITE() { _Pragma("unroll") for (int i_ = 0; i_ < 2; ++i_){ \
        int rb_ = (r0 + 8*i_)*4; int kk_ = rb_ ^ (8*(c4 & 7)); \
        _Pragma("unroll") for (int cc_ = 0; cc_ < 4; ++cc_){ \
            int d_ = c4*4 + cc_; \
            u16x4 pk_ = { f2bf(vpre[i_][0][cc_]), f2bf(vpre[i_][1][cc_]), \
                          f2bf(vpre[i_][2][cc_]), f2bf(vpre[i_][3][cc_]) }; \
            *(u16x4*)(&vT_s[d_*KT + kk_]) = pk_; } } }

#define M_LOAD(DST, T) if (USE_BITS){ _Pragma("unroll") for (int r_ = 0; r_ < 4; ++r_) DST[r_] = mbr[r_][(T)]; }

    // ================= pass 1: row sums of exp =================
    float rs[4] = {0.f, 0.f, 0.f, 0.f};
    K_LOAD(0); M_LOAD(mc, 0);
    for (int t = 0; t < NT; ++t){
        __syncthreads();
        K_WRITE();
        if (t+1 < NT){ K_LOAD(t+1); M_LOAD(mn, t+1); }
        __syncthreads();
        #pragma unroll
        for (int cg = 0; cg < 4; ++cg){
            f32x4 acc = {0.f, 0.f, 0.f, 0.f};
            const int krow = cg*16 + ln15;
            const unsigned short* kb = &k_s[krow*DD];
            const int sw = 8*(krow & 7);
            #pragma unroll
            for (int c = 0; c < 4; ++c){
                bf16x8 bf = *(const bf16x8*)(kb + ((c*32 + g*8) ^ sw));
                acc = __builtin_amdgcn_mfma_f32_16x16x32_bf16(qa[c], bf, acc, 0, 0, 0);
            }
            const int kc = cg*16 + ln15;
            #pragma unroll
            for (int r = 0; r < 4; ++r){
                bool msk;
                if (USE_BITS) msk = (mc[r] >> kc) & 1ull;
                else          msk = maskb[((mrow[r] + t*KT + kc) << msh) + madd] != 0;
                rs[r] += msk ? 0.f : __expf(acc[r] * SCALE);
            }
        }
        if (USE_BITS){
            #pragma unroll
            for (int r = 0; r < 4; ++r) mc[r] = mn[r];
        }
    }

    float invl[4];
    #pragma unroll
    for (int r = 0; r < 4; ++r){
        float s = rs[r];
        s += __shfl_xor(s, 1); s += __shfl_xor(s, 2);
        s += __shfl_xor(s, 4); s += __shfl_xor(s, 8);
        invl[r] = 1.0f / s;
    }

    f32x4 oacc[8];
    #pragma unroll
    for (int d8 = 0; d8 < 8; ++d8) oacc[d8] = (f32x4){0.f, 0.f, 0.f, 0.f};

    // ================= pass 2: attn write + PV =================
    K_LOAD(0); V_LOAD(0); M_LOAD(mc, 0);
    for (int t = 0; t < NT; ++t){
        __syncthreads();
        K_WRITE(); V_WRITE();
        if (t+1 < NT){ K_LOAD(t+1); V_LOAD(t+1); M_LOAD(mn, t+1); }
        __syncthreads();
        float* pw = &p_f[w*1024];
        #pragma unroll
        for (int cg = 0; cg < 4; ++cg){
            f32x4 acc = {0.f, 0.f, 0.f, 0.f};
            const int krow = cg*16 + ln15;
            const unsigned short* kb = &k_s[krow*DD];
            const int sw = 8*(krow & 7);
            #pragma unroll
            for (int c = 0; c < 4; ++c){
                bf16x8 bf = *(const bf16x8*)(kb + ((c*32 + g*8) ^ sw));
                acc = __builtin_amdgcn_mfma_f32_16x16x32_bf16(qa[c], bf, acc, 0, 0, 0);
            }
            const int kc = cg*16 + ln15;
            #pragma unroll
            for (int r = 0; r < 4; ++r){
                bool msk;
                if (USE_BITS) msk = (mc[r] >> kc) & 1ull;
                else          msk = maskb[((mrow[r] + t*KT + kc) << msh) + madd] != 0;
                float p = msk ? 0.f : __expf(acc[r] * SCALE) * invl[r];
                int prow = 4*g + r;
                pw[prow*64 + (kc ^ (8*g))] = p;   // swizzle by writer row-group
            }
        }
        // vectorized attn stores (wave-private LDS, in-order DS pipe)
        #pragma unroll
        for (int it = 0; it < 4; ++it){
            int row = it*4 + g;
            f32x4 val = *(const f32x4*)(&pw[row*64 + ((ln15*4) ^ (8*it))]);
            *(f32x4*)(&attn[((size_t)bb*LL + qw0 + row)*(size_t)LL + t*KT + ln15*4]) = val;
        }
        // PV: A-frags from f32 P (convert), B-frags from swizzled vT
        const float* par = &p_f[w*1024 + ln15*64];
        const int e2 = 8*((ln15 >> 2) & 3);
        bf16x8 pa0, pa1;
        {
            const float* s0 = par + ((g*8) ^ e2);
            const float* s1 = par + ((32 + g*8) ^ e2);
            #pragma unroll
            for (int j = 0; j < 8; ++j){
                pa0[j] = (short)f2bf(s0[j]);
                pa1[j] = (short)f2bf(s1[j]);
            }
        }
        #pragma unroll
        for (int d8 = 0; d8 < 8; ++d8){
            const int d = d8*16 + ln15;
            const unsigned short* vb = &vT_s[d*KT];
            const int ev = 8*((4*d8 + (ln15 >> 2)) & 7);
            bf16x8 b0 = *(const bf16x8*)(vb + ((g*8) ^ ev));
            bf16x8 b1 = *(const bf16x8*)(vb + ((32 + g*8) ^ ev));
            oacc[d8] = __builtin_amdgcn_mfma_f32_16x16x32_bf16(pa0, b0, oacc[d8], 0, 0, 0);
            oacc[d8] = __builtin_amdgcn_mfma_f32_16x16x32_bf16(pa1, b1, oacc[d8], 0, 0, 0);
        }
        if (USE_BITS){
            #pragma unroll
            for (int r = 0; r < 4; ++r) mc[r] = mn[r];
        }
    }

    // epilogue: write O
    #pragma unroll
    for (int d8 = 0; d8 < 8; ++d8){
        #pragma unroll
        for (int r = 0; r < 4; ++r){
            out[((size_t)bb*LL + qw0 + 4*g + r)*DD + d8*16 + ln15] = oacc[d8][r];
        }
    }
#undef K_LOAD
#undef K_WRITE
#undef V_LOAD
#undef V_WRITE
#undef M_LOAD
}

extern "C" void kernel_launch(void* const* d_in, const int* in_sizes, int n_in,
                              void* d_out, int out_size, void* d_ws, size_t ws_size,
                              hipStream_t stream)
{
    const float* q = (const float*)d_in[0];
    const float* k = (const float*)d_in[1];
    const float* v = (const float*)d_in[2];
    const unsigned char* mask = (const unsigned char*)d_in[3];
    int* flag = (int*)d_ws;
    u64* mb = (u64*)((char*)d_ws + 256);

    float* out  = (float*)d_out;
    float* attn = out + (size_t)BB*LL*DD;

    const size_t need = 256 + (size_t)BB*LL*NT*sizeof(u64);   // ~8.4 MB
    const bool use_bits = ws_size >= need;

    detect_mask<<<1, 64, 0, stream>>>((const unsigned*)mask, flag);
    if (use_bits){
        prepack_mask<<<(BB*LL*NT)/THREADS, THREADS, 0, stream>>>(mask, flag, mb);
        attn_fused<1><<<NWG, THREADS, 0, stream>>>(q, k, v, mask, flag, mb, out, attn);
    } else {
        attn_fused<0><<<NWG, THREADS, 0, stream>>>(q, k, v, mask, flag, mb, out, attn);
    }
}

// Round 3
// 453.586 us; speedup vs baseline: 1.5825x; 1.1404x over previous
//
#include <hip/hip_runtime.h>

#define BB 16
#define LL 2048
#define DD 128
#define SCALE 0.03125f   // 1/sqrt(1024)

#define QT 64
#define KT 64
#define NT (LL/KT)       // 32
#define SPLIT 2
#define HKT (NT/SPLIT)   // 16
#define THREADS 256
#define NWG  (BB*(LL/QT))        // 512  (fallback grid)
#define NWGS (BB*SPLIT*(LL/QT))  // 1024 (split grids)

using bf16x8 = __attribute__((ext_vector_type(8))) short;
using f32x4  = __attribute__((ext_vector_type(4))) float;
using u16x4  = __attribute__((ext_vector_type(4))) unsigned short;
typedef unsigned long long u64;

__device__ __forceinline__ unsigned short f2bf(float f){
    union { float f; unsigned u; } a; a.f = f;
    unsigned r = a.u + 0x7FFFu + ((a.u >> 16) & 1u);
    return (unsigned short)(r >> 16);
}

// Detect mask element layout: 0 = 4-byte int, 1 = 1-byte bool, 2 = 4-byte float.
__global__ void detect_mask(const unsigned* __restrict__ m, int* __restrict__ flag){
    int lane = threadIdx.x & 63;
    unsigned hi = 0, nl = 0;
    #pragma unroll
    for (int i = 0; i < 16; ++i){
        unsigned d = m[lane*16 + i];
        hi |= (d & 0xFFFFFF00u);
        nl |= (d & 0xFEFEFEFEu);
    }
    unsigned long long bh = __ballot(hi != 0u);
    unsigned long long bn = __ballot(nl != 0u);
    if (lane == 0){
        int f = 0;
        if (bn != 0ull) f = 2;
        else if (bh != 0ull) f = 1;
        flag[0] = f;
    }
}

__global__ void prepack_mask(const unsigned char* __restrict__ m,
                             const int* __restrict__ flagp,
                             u64* __restrict__ mb){
    int id = blockIdx.x * THREADS + threadIdx.x;
    int fl = flagp[0];
    u64 bits = 0;
    if (fl == 1){
        const uint4* mp = (const uint4*)(m + (size_t)id * 64);
        #pragma unroll
        for (int c = 0; c < 4; ++c){
            uint4 u = mp[c];
            unsigned wd[4] = {u.x, u.y, u.z, u.w};
            #pragma unroll
            for (int wi = 0; wi < 4; ++wi){
                #pragma unroll
                for (int b = 0; b < 4; ++b)
                    if ((wd[wi] >> (8*b)) & 0xFFu) bits |= 1ull << (c*16 + wi*4 + b);
            }
        }
    } else {
        const uint4* mp = (const uint4*)m + (size_t)id * 16;
        #pragma unroll
        for (int c = 0; c < 16; ++c){
            uint4 u = mp[c];
            if (u.x) bits |= 1ull << (c*4+0);
            if (u.y) bits |= 1ull << (c*4+1);
            if (u.z) bits |= 1ull << (c*4+2);
            if (u.w) bits |= 1ull << (c*4+3);
        }
    }
    mb[id] = bits;
}

// ---------------- staging macros (shared by kernels) ----------------
#define K_LOAD(T) { const float* kp_ = kbase + (size_t)(T)*KT*DD; \
    _Pragma("unroll") for (int i_ = 0; i_ < 8; ++i_) \
        kpre[i_] = *(const f32x4*)(kp_ + (i_*8 + r0)*DD + c4*4); }

#define K_WRITE() { _Pragma("unroll") for (int i_ = 0; i_ < 8; ++i_){ \
        int row_ = i_*8 + r0; int e_ = (c4*4) ^ (8*(row_ & 7)); \
        u16x4 pk_ = { f2bf(kpre[i_][0]), f2bf(kpre[i_][1]), f2bf(kpre[i_][2]), f2bf(kpre[i_][3]) }; \
        *(u16x4*)(&k_s[row_*DD + e_]) = pk_; } }

#define V_LOAD(T) { const float* vp_ = vbase + (size_t)(T)*KT*DD; \
    _Pragma("unroll") for (int i_ = 0; i_ < 2; ++i_) \
        _Pragma("unroll") for (int rr_ = 0; rr_ < 4; ++rr_) \
            vpre[i_][rr_] = *(const f32x4*)(vp_ + ((r0 + 8*i_)*4 + rr_)*DD + c4*4); }

#define V_WRITE() { _Pragma("unroll") for (int i_ = 0; i_ < 2; ++i_){ \
        int rb_ = (r0 + 8*i_)*4; int kk_ = rb_ ^ (8*(c4 & 7)); \
        _Pragma("unroll") for (int cc_ = 0; cc_ < 4; ++cc_){ \
            int d_ = c4*4 + cc_; \
            u16x4 pk_ = { f2bf(vpre[i_][0][cc_]), f2bf(vpre[i_][1][cc_]), \
                          f2bf(vpre[i_][2][cc_]), f2bf(vpre[i_][3][cc_]) }; \
            *(u16x4*)(&vT_s[d_*KT + kk_]) = pk_; } } }

#define M_LOAD(DST, T) { _Pragma("unroll") for (int r_ = 0; r_ < 4; ++r_) DST[r_] = mbr[r_][(T)]; }

#define QK_MFMA(ACC, CG) { \
    const int krow_ = (CG)*16 + ln15; \
    const unsigned short* kb_ = &k_s[krow_*DD]; \
    const int sw_ = 8*(krow_ & 7); \
    _Pragma("unroll") for (int c_ = 0; c_ < 4; ++c_){ \
        bf16x8 bf_ = *(const bf16x8*)(kb_ + ((c_*32 + g*8) ^ sw_)); \
        ACC = __builtin_amdgcn_mfma_f32_16x16x32_bf16(qa[c_], bf_, ACC, 0, 0, 0); } }

#define Q_FRAGS() { \
    const float* qp_ = q + ((size_t)bb*LL + qw0 + ln15)*DD + g*8; \
    _Pragma("unroll") for (int c_ = 0; c_ < 4; ++c_){ \
        f32x4 x_ = *(const f32x4*)(qp_ + c_*32); \
        f32x4 y_ = *(const f32x4*)(qp_ + c_*32 + 4); \
        bf16x8 t_; \
        t_[0]=(short)f2bf(x_[0]); t_[1]=(short)f2bf(x_[1]); t_[2]=(short)f2bf(x_[2]); t_[3]=(short)f2bf(x_[3]); \
        t_[4]=(short)f2bf(y_[0]); t_[5]=(short)f2bf(y_[1]); t_[6]=(short)f2bf(y_[2]); t_[7]=(short)f2bf(y_[3]); \
        qa[c_] = t_; } }

// ================= split kernel 1: partial row sums =================
__global__ __launch_bounds__(THREADS, 4) void attn_sums(
    const float* __restrict__ q, const float* __restrict__ k,
    const u64* __restrict__ mb, float* __restrict__ lpart)
{
    __shared__ __attribute__((aligned(16))) unsigned short k_s[KT*DD];

    const int tid  = threadIdx.x;
    const int w    = tid >> 6;
    const int lane = tid & 63;
    const int ln15 = lane & 15;
    const int g    = lane >> 4;
    const int r0   = tid >> 5;
    const int c4   = tid & 31;

    const int hw   = blockIdx.x;
    const int bidx = (hw & 7) * (NWGS/8) + (hw >> 3);   // XCD-contiguous logical id
    const int bb   = bidx >> 6;
    const int half = (bidx >> 5) & 1;
    const int qt0  = (bidx & 31) * QT;
    const int qw0  = qt0 + w*16;

    bf16x8 qa[4];
    Q_FRAGS();

    const u64* mbr[4];
    #pragma unroll
    for (int r = 0; r < 4; ++r)
        mbr[r] = mb + ((size_t)bb*LL + qw0 + 4*g + r) * NT;

    const float* kbase = k + (size_t)bb*LL*DD;
    f32x4 kpre[8];
    u64 mc[4], mn[4];

    const int T0 = half * HKT;
    float rs[4] = {0.f, 0.f, 0.f, 0.f};
    K_LOAD(T0); M_LOAD(mc, T0);
    for (int tt = 0; tt < HKT; ++tt){
        const int t = T0 + tt;
        __syncthreads();
        K_WRITE();
        if (tt+1 < HKT){ K_LOAD(t+1); M_LOAD(mn, t+1); }
        __syncthreads();
        #pragma unroll
        for (int cg = 0; cg < 4; ++cg){
            f32x4 acc = {0.f, 0.f, 0.f, 0.f};
            QK_MFMA(acc, cg);
            const int kc = cg*16 + ln15;
            #pragma unroll
            for (int r = 0; r < 4; ++r){
                bool msk = (mc[r] >> kc) & 1ull;
                rs[r] += msk ? 0.f : __expf(acc[r] * SCALE);
            }
        }
        #pragma unroll
        for (int r = 0; r < 4; ++r) mc[r] = mn[r];
    }
    #pragma unroll
    for (int r = 0; r < 4; ++r){
        float s = rs[r];
        s += __shfl_xor(s, 1); s += __shfl_xor(s, 2);
        s += __shfl_xor(s, 4); s += __shfl_xor(s, 8);
        if (ln15 == 0)
            lpart[(size_t)half*BB*LL + (size_t)bb*LL + qw0 + 4*g + r] = s;
    }
}

// ============ split kernel 2: attn write + partial PV ============
__global__ __launch_bounds__(THREADS, 3) void attn_main(
    const float* __restrict__ q, const float* __restrict__ k, const float* __restrict__ v,
    const u64* __restrict__ mb, const float* __restrict__ lpart,
    float* __restrict__ attn, float* __restrict__ pO)
{
    __shared__ __attribute__((aligned(16))) unsigned short k_s[KT*DD];
    __shared__ __attribute__((aligned(16))) unsigned short vT_s[DD*KT];
    __shared__ __attribute__((aligned(16))) float p_f[4*16*64];

    const int tid  = threadIdx.x;
    const int w    = tid >> 6;
    const int lane = tid & 63;
    const int ln15 = lane & 15;
    const int g    = lane >> 4;
    const int r0   = tid >> 5;
    const int c4   = tid & 31;

    const int hw   = blockIdx.x;
    const int bidx = (hw & 7) * (NWGS/8) + (hw >> 3);
    const int bb   = bidx >> 6;
    const int half = (bidx >> 5) & 1;
    const int qt0  = (bidx & 31) * QT;
    const int qw0  = qt0 + w*16;

    bf16x8 qa[4];
    Q_FRAGS();

    const u64* mbr[4];
    float invl[4];
    #pragma unroll
    for (int r = 0; r < 4; ++r){
        size_t row = (size_t)bb*LL + qw0 + 4*g + r;
        mbr[r] = mb + row * NT;
        invl[r] = 1.0f / (lpart[row] + lpart[(size_t)BB*LL + row]);
    }

    const float* kbase = k + (size_t)bb*LL*DD;
    const float* vbase = v + (size_t)bb*LL*DD;
    f32x4 kpre[8];
    f32x4 vpre[2][4];
    u64 mc[4], mn[4];

    f32x4 oacc[8];
    #pragma unroll
    for (int d8 = 0; d8 < 8; ++d8) oacc[d8] = (f32x4){0.f, 0.f, 0.f, 0.f};

    const int T0 = half * HKT;
    K_LOAD(T0); V_LOAD(T0); M_LOAD(mc, T0);
    for (int tt = 0; tt < HKT; ++tt){
        const int t = T0 + tt;
        __syncthreads();
        K_WRITE(); V_WRITE();
        if (tt+1 < HKT){ K_LOAD(t+1); V_LOAD(t+1); M_LOAD(mn, t+1); }
        __syncthreads();
        float* pw = &p_f[w*1024];
        #pragma unroll
        for (int cg = 0; cg < 4; ++cg){
            f32x4 acc = {0.f, 0.f, 0.f, 0.f};
            QK_MFMA(acc, cg);
            const int kc = cg*16 + ln15;
            #pragma unroll
            for (int r = 0; r < 4; ++r){
                bool msk = (mc[r] >> kc) & 1ull;
                float p = msk ? 0.f : __expf(acc[r] * SCALE) * invl[r];
                int prow = 4*g + r;
                pw[prow*64 + (kc ^ (8*g))] = p;
            }
        }
        // vectorized attn stores
        #pragma unroll
        for (int it = 0; it < 4; ++it){
            int row = it*4 + g;
            f32x4 val = *(const f32x4*)(&pw[row*64 + ((ln15*4) ^ (8*it))]);
            *(f32x4*)(&attn[((size_t)bb*LL + qw0 + row)*(size_t)LL + t*KT + ln15*4]) = val;
        }
        // PV
        const float* par = &p_f[w*1024 + ln15*64];
        const int e2 = 8*((ln15 >> 2) & 3);
        bf16x8 pa0, pa1;
        {
            const float* s0 = par + ((g*8) ^ e2);
            const float* s1 = par + ((32 + g*8) ^ e2);
            #pragma unroll
            for (int j = 0; j < 8; ++j){
                pa0[j] = (short)f2bf(s0[j]);
                pa1[j] = (short)f2bf(s1[j]);
            }
        }
        #pragma unroll
        for (int d8 = 0; d8 < 8; ++d8){
            const int d = d8*16 + ln15;
            const unsigned short* vb = &vT_s[d*KT];
            const int ev = 8*((4*d8 + (ln15 >> 2)) & 7);
            bf16x8 b0 = *(const bf16x8*)(vb + ((g*8) ^ ev));
            bf16x8 b1 = *(const bf16x8*)(vb + ((32 + g*8) ^ ev));
            oacc[d8] = __builtin_amdgcn_mfma_f32_16x16x32_bf16(pa0, b0, oacc[d8], 0, 0, 0);
            oacc[d8] = __builtin_amdgcn_mfma_f32_16x16x32_bf16(pa1, b1, oacc[d8], 0, 0, 0);
        }
        #pragma unroll
        for (int r = 0; r < 4; ++r) mc[r] = mn[r];
    }

    // epilogue: partial O
    float* po = pO + (size_t)half*BB*LL*DD;
    #pragma unroll
    for (int d8 = 0; d8 < 8; ++d8){
        #pragma unroll
        for (int r = 0; r < 4; ++r){
            po[((size_t)bb*LL + qw0 + 4*g + r)*DD + d8*16 + ln15] = oacc[d8][r];
        }
    }
}

__global__ void combine_out(const float* __restrict__ pO, float* __restrict__ out){
    size_t i = ((size_t)blockIdx.x*THREADS + threadIdx.x) * 4;
    f32x4 a = *(const f32x4*)(pO + i);
    f32x4 b = *(const f32x4*)(pO + (size_t)BB*LL*DD + i);
    *(f32x4*)(out + i) = a + b;
}

// ================= fallback: fused two-pass (round-2 kernel) =================
template<int USE_BITS>
__global__ __launch_bounds__(THREADS, 3) void attn_fused(
    const float* __restrict__ q, const float* __restrict__ k, const float* __restrict__ v,
    const unsigned char* __restrict__ maskb, const int* __restrict__ flagp,
    const u64* __restrict__ mb,
    float* __restrict__ out, float* __restrict__ attn)
{
    __shared__ __attribute__((aligned(16))) unsigned short k_s[KT*DD];
    __shared__ __attribute__((aligned(16))) unsigned short vT_s[DD*KT];
    __shared__ __attribute__((aligned(16))) float p_f[4*16*64];

    const int tid  = threadIdx.x;
    const int w    = tid >> 6;
    const int lane = tid & 63;
    const int ln15 = lane & 15;
    const int g    = lane >> 4;
    const int r0   = tid >> 5;
    const int c4   = tid & 31;

    const int bidx = blockIdx.x;
    const int bb   = bidx >> 5;
    const int qt0  = (bidx & 31) * QT;
    const int qw0  = qt0 + w*16;

    int msh = 0, madd = 0;
    if (!USE_BITS){
        const int mflag = flagp[0];
        msh  = (mflag == 1) ? 0 : 2;
        madd = (mflag == 2) ? 3 : 0;
    }

    bf16x8 qa[4];
    Q_FRAGS();

    size_t mrow[4];
    const u64* mbr[4];
    #pragma unroll
    for (int r = 0; r < 4; ++r){
        size_t qrow = (size_t)bb*LL + qw0 + 4*g + r;
        mrow[r] = qrow * (size_t)LL;
        mbr[r]  = mb + qrow * NT;
    }

    const float* kbase = k + (size_t)bb*LL*DD;
    const float* vbase = v + (size_t)bb*LL*DD;

    f32x4 kpre[8];
    f32x4 vpre[2][4];
    u64 mc[4] = {0,0,0,0}, mn[4] = {0,0,0,0};

    float rs[4] = {0.f, 0.f, 0.f, 0.f};
    K_LOAD(0); if (USE_BITS) M_LOAD(mc, 0);
    for (int t = 0; t < NT; ++t){
        __syncthreads();
        K_WRITE();
        if (t+1 < NT){ K_LOAD(t+1); if (USE_BITS) M_LOAD(mn, t+1); }
        __syncthreads();
        #pragma unroll
        for (int cg = 0; cg < 4; ++cg){
            f32x4 acc = {0.f, 0.f, 0.f, 0.f};
            QK_MFMA(acc, cg);
            const int kc = cg*16 + ln15;
            #pragma unroll
            for (int r = 0; r < 4; ++r){
                bool msk;
                if (USE_BITS) msk = (mc[r] >> kc) & 1ull;
                else          msk = maskb[((mrow[r] + t*KT + kc) << msh) + madd] != 0;
                rs[r] += msk ? 0.f : __expf(acc[r] * SCALE);
            }
        }
        if (USE_BITS){
            #pragma unroll
            for (int r = 0; r < 4; ++r) mc[r] = mn[r];
        }
    }

    float invl[4];
    #pragma unroll
    for (int r = 0; r < 4; ++r){
        float s = rs[r];
        s += __shfl_xor(s, 1); s += __shfl_xor(s, 2);
        s += __shfl_xor(s, 4); s += __shfl_xor(s, 8);
        invl[r] = 1.0f / s;
    }

    f32x4 oacc[8];
    #pragma unroll
    for (int d8 = 0; d8 < 8; ++d8) oacc[d8] = (f32x4){0.f, 0.f, 0.f, 0.f};

    K_LOAD(0); V_LOAD(0); if (USE_BITS) M_LOAD(mc, 0);
    for (int t = 0; t < NT; ++t){
        __syncthreads();
        K_WRITE(); V_WRITE();
        if (t+1 < NT){ K_LOAD(t+1); V_LOAD(t+1); if (USE_BITS) M_LOAD(mn, t+1); }
        __syncthreads();
        float* pw = &p_f[w*1024];
        #pragma unroll
        for (int cg = 0; cg < 4; ++cg){
            f32x4 acc = {0.f, 0.f, 0.f, 0.f};
            QK_MFMA(acc, cg);
            const int kc = cg*16 + ln15;
            #pragma unroll
            for (int r = 0; r < 4; ++r){
                bool msk;
                if (USE_BITS) msk = (mc[r] >> kc) & 1ull;
                else          msk = maskb[((mrow[r] + t*KT + kc) << msh) + madd] != 0;
                float p = msk ? 0.f : __expf(acc[r] * SCALE) * invl[r];
                int prow = 4*g + r;
                pw[prow*64 + (kc ^ (8*g))] = p;
            }
        }
        #pragma unroll
        for (int it = 0; it < 4; ++it){
            int row = it*4 + g;
            f32x4 val = *(const f32x4*)(&pw[row*64 + ((ln15*4) ^ (8*it))]);
            *(f32x4*)(&attn[((size_t)bb*LL + qw0 + row)*(size_t)LL + t*KT + ln15*4]) = val;
        }
        const float* par = &p_f[w*1024 + ln15*64];
        const int e2 = 8*((ln15 >> 2) & 3);
        bf16x8 pa0, pa1;
        {
            const float* s0 = par + ((g*8) ^ e2);
            const float* s1 = par + ((32 + g*8) ^ e2);
            #pragma unroll
            for (int j = 0; j < 8; ++j){
                pa0[j] = (short)f2bf(s0[j]);
                pa1[j] = (short)f2bf(s1[j]);
            }
        }
        #pragma unroll
        for (int d8 = 0; d8 < 8; ++d8){
            const int d = d8*16 + ln15;
            const unsigned short* vb = &vT_s[d*KT];
            const int ev = 8*((4*d8 + (ln15 >> 2)) & 7);
            bf16x8 b0 = *(const bf16x8*)(vb + ((g*8) ^ ev));
            bf16x8 b1 = *(const bf16x8*)(vb + ((32 + g*8) ^ ev));
            oacc[d8] = __builtin_amdgcn_mfma_f32_16x16x32_bf16(pa0, b0, oacc[d8], 0, 0, 0);
            oacc[d8] = __builtin_amdgcn_mfma_f32_16x16x32_bf16(pa1, b1, oacc[d8], 0, 0, 0);
        }
        if (USE_BITS){
            #pragma unroll
            for (int r = 0; r < 4; ++r) mc[r] = mn[r];
        }
    }

    #pragma unroll
    for (int d8 = 0; d8 < 8; ++d8){
        #pragma unroll
        for (int r = 0; r < 4; ++r){
            out[((size_t)bb*LL + qw0 + 4*g + r)*DD + d8*16 + ln15] = oacc[d8][r];
        }
    }
}

extern "C" void kernel_launch(void* const* d_in, const int* in_sizes, int n_in,
                              void* d_out, int out_size, void* d_ws, size_t ws_size,
                              hipStream_t stream)
{
    const float* q = (const float*)d_in[0];
    const float* k = (const float*)d_in[1];
    const float* v = (const float*)d_in[2];
    const unsigned char* mask = (const unsigned char*)d_in[3];

    float* out  = (float*)d_out;
    float* attn = out + (size_t)BB*LL*DD;

    const size_t bits_sz = (size_t)BB*LL*NT*sizeof(u64);      // 8 MB
    const size_t off_l   = 256 + bits_sz;
    const size_t l_sz    = (size_t)SPLIT*BB*LL*sizeof(float); // 256 KB
    const size_t off_pO  = off_l + l_sz;
    const size_t pO_sz   = (size_t)SPLIT*BB*LL*DD*sizeof(float); // 32 MB
    const size_t need_split = off_pO + pO_sz;
    const size_t need_bits  = 256 + bits_sz;

    int*   flag  = (int*)d_ws;
    u64*   mb    = (u64*)((char*)d_ws + 256);
    float* lpart = (float*)((char*)d_ws + off_l);
    float* pO    = (float*)((char*)d_ws + off_pO);

    detect_mask<<<1, 64, 0, stream>>>((const unsigned*)mask, flag);
    if (ws_size >= need_split){
        prepack_mask<<<(BB*LL*NT)/THREADS, THREADS, 0, stream>>>(mask, flag, mb);
        attn_sums<<<NWGS, THREADS, 0, stream>>>(q, k, mb, lpart);
        attn_main<<<NWGS, THREADS, 0, stream>>>(q, k, v, mb, lpart, attn, pO);
        combine_out<<<(BB*LL*DD)/(4*THREADS), THREADS, 0, stream>>>(pO, out);
    } else if (ws_size >= need_bits){
        prepack_mask<<<(BB*LL*NT)/THREADS, THREADS, 0, stream>>>(mask, flag, mb);
        attn_fused<1><<<NWG, THREADS, 0, stream>>>(q, k, v, mask, flag, mb, out, attn);
    } else {
        attn_fused<0><<<NWG, THREADS, 0, stream>>>(q, k, v, mask, flag, mb, out, attn);
    }
}